// Round 2
// baseline (715.820 us; speedup 1.0000x reference)
//
#include <hip/hip_runtime.h>
#include <stdint.h>

// ---- problem constants ----
#define B_ 4
#define S_ 1024
#define E_ 1024
#define H_ 16
#define D_ 64

typedef unsigned short u16;
typedef short s16x8 __attribute__((ext_vector_type(8)));
typedef unsigned short u16x8 __attribute__((ext_vector_type(8)));
typedef unsigned short u16x4 __attribute__((ext_vector_type(4)));
typedef float f32x4 __attribute__((ext_vector_type(4)));

__device__ __forceinline__ u16 f2bf(float f) {
    union { float f; uint32_t i; } x; x.f = f;
    uint32_t r = (x.i + 0x7FFFu + ((x.i >> 16) & 1u)) >> 16;
    return (u16)r;
}

__device__ __forceinline__ float wave_max(float v) {
    #pragma unroll
    for (int o = 32; o; o >>= 1) v = fmaxf(v, __shfl_xor(v, o));
    return v;
}
__device__ __forceinline__ float wave_sum(float v) {
    #pragma unroll
    for (int o = 32; o; o >>= 1) v += __shfl_xor(v, o);
    return v;
}

// =====================================================================
// Generic GEMM: C = A (M x K, row stride lda) * BT^T, BT is (N x K, ldb),
// BT always bf16.  A is f32 (AF32=true, converted during staging) or bf16.
// MFMA 16x16x32_bf16, 256 threads = 4 waves (2x2), wave tile (BM/2)x(BN/2).
// EPI: 0 = out proj   -> f32 C[row*ldc+col] + bias
//      1 = Q/K proj   -> bf16 [b][h][s][d] + bias
//      2 = V proj     -> bf16 [b][h][d][s] (transposed) + bias
//      3 = scores     -> f32 val*alpha + phi[h], at z*S*S + row*S + col
//      4 = PV ctx     -> bf16 [b][q][h*D+d]
// =====================================================================
template<int BM, int BN, int EPI, bool AF32>
__global__ __launch_bounds__(256)
void gemm_bt(const void* __restrict__ Avoid, int lda, long sA,
             const u16* __restrict__ BT, int ldb, long sB,
             const float* __restrict__ bias,
             void* __restrict__ Cvoid, int ldc,
             int K, float alpha, const float* __restrict__ phib)
{
    constexpr int BK = 32;
    constexpr int FM = BM / 32;
    constexpr int FN = BN / 32;
    __shared__ __attribute__((aligned(16))) u16 As[BM * BK];
    __shared__ __attribute__((aligned(16))) u16 Bs[BN * BK];

    const int t = threadIdx.x;
    const int lane = t & 63;
    const int wave = t >> 6;
    const int wr = wave >> 1, wc = wave & 1;
    const int z = blockIdx.z;
    const int m0 = blockIdx.y * BM, n0 = blockIdx.x * BN;

    const u16* Bp = BT + (size_t)z * sB;

    f32x4 acc[FM][FN];
    #pragma unroll
    for (int i = 0; i < FM; i++)
        #pragma unroll
        for (int j = 0; j < FN; j++)
            acc[i][j] = (f32x4){0.f, 0.f, 0.f, 0.f};

    const int al = lane & 15;   // m (A) / n (B) / col (C)
    const int aq = lane >> 4;   // k-quad

    for (int k0 = 0; k0 < K; k0 += BK) {
        __syncthreads();
        // ---- stage A tile [BM][BK] ----
        if (AF32) {
            const float* Af = ((const float*)Avoid) + (size_t)z * sA;
            #pragma unroll
            for (int p = 0; p < (BM * BK) / 4; p += 256) {
                int c = p + t;
                int row = c >> 3, cc = c & 7;
                f32x4 v = *(const f32x4*)(Af + (size_t)(m0 + row) * lda + k0 + cc * 4);
                u16x4 o;
                o[0] = f2bf(v[0]); o[1] = f2bf(v[1]);
                o[2] = f2bf(v[2]); o[3] = f2bf(v[3]);
                *(u16x4*)(As + c * 4) = o;
            }
        } else {
            const u16* Ap = ((const u16*)Avoid) + (size_t)z * sA;
            #pragma unroll
            for (int p = 0; p < (BM * BK) / 8; p += 256) {
                int c = p + t;
                int row = c >> 2, cc = c & 3;
                u16x8 v = *(const u16x8*)(Ap + (size_t)(m0 + row) * lda + k0 + cc * 8);
                *(u16x8*)(As + c * 8) = v;
            }
        }
        // ---- stage BT tile [BN][BK] (bf16) ----
        #pragma unroll
        for (int p = 0; p < (BN * BK) / 8; p += 256) {
            int c = p + t;
            int row = c >> 2, cc = c & 3;
            u16x8 v = *(const u16x8*)(Bp + (size_t)(n0 + row) * ldb + k0 + cc * 8);
            *(u16x8*)(Bs + c * 8) = v;
        }
        __syncthreads();

        s16x8 af[FM], bf[FN];
        #pragma unroll
        for (int i = 0; i < FM; i++)
            af[i] = *(const s16x8*)(As + ((wr * FM + i) * 16 + al) * BK + aq * 8);
        #pragma unroll
        for (int j = 0; j < FN; j++)
            bf[j] = *(const s16x8*)(Bs + ((wc * FN + j) * 16 + al) * BK + aq * 8);
        #pragma unroll
        for (int i = 0; i < FM; i++)
            #pragma unroll
            for (int j = 0; j < FN; j++)
                acc[i][j] = __builtin_amdgcn_mfma_f32_16x16x32_bf16(af[i], bf[j], acc[i][j], 0, 0, 0);
    }

    // epilogue: C/D layout: col = al, row = aq*4 + r
    float* Cf = (float*)Cvoid;
    u16*   Cb = (u16*)Cvoid;
    #pragma unroll
    for (int i = 0; i < FM; i++) {
        #pragma unroll
        for (int j = 0; j < FN; j++) {
            const int col = n0 + (wc * FN + j) * 16 + al;
            float bv = 0.f;
            if (EPI == 0 || EPI == 1 || EPI == 2) bv = bias[col];
            #pragma unroll
            for (int r = 0; r < 4; r++) {
                const int row = m0 + (wr * FM + i) * 16 + aq * 4 + r;
                float v = acc[i][j][r];
                if (EPI == 0) {
                    Cf[(size_t)row * ldc + col] = v + bv;
                } else if (EPI == 1) {
                    int b = row >> 10, s = row & 1023, h = col >> 6, d = col & 63;
                    Cb[((size_t)((b * H_ + h) * S_ + s)) * D_ + d] = f2bf(v + bv);
                } else if (EPI == 2) {
                    int b = row >> 10, s = row & 1023, h = col >> 6, d = col & 63;
                    Cb[((size_t)((b * H_ + h) * D_ + d)) * S_ + s] = f2bf(v + bv);
                } else if (EPI == 3) {
                    int h = z & (H_ - 1);
                    Cf[(size_t)z * S_ * S_ + (size_t)row * S_ + col] = v * alpha + phib[h];
                } else { // EPI == 4
                    int b = z >> 4, h = z & 15;
                    Cb[((size_t)(b * S_ + row)) * E_ + h * D_ + col] = f2bf(v);
                }
            }
        }
    }
}

// =====================================================================
// consciousness weights: logits = query @ Wc + bc (E x 16 f32), softmax
// over 16 heads, m = 1 + cl*cw, stored mws[(b*H+h)*S + s] (f32).
// One wave per (b,s) row.
// =====================================================================
__global__ __launch_bounds__(256)
void cons_k(const float* __restrict__ query, const float* __restrict__ Wc,
            const float* __restrict__ bc, const float* __restrict__ cl,
            float* __restrict__ mws)
{
    const int t = threadIdx.x, lane = t & 63, wave = t >> 6;
    const int r = blockIdx.x * 4 + wave;   // row in [0, B*S)
    const float* qrow = query + (size_t)r * E_;
    float acc[H_];
    #pragma unroll
    for (int c = 0; c < H_; c++) acc[c] = 0.f;
    for (int e = lane; e < E_; e += 64) {
        float qv = qrow[e];
        const float* wp = Wc + e * H_;
        f32x4 w0 = *(const f32x4*)(wp);
        f32x4 w1 = *(const f32x4*)(wp + 4);
        f32x4 w2 = *(const f32x4*)(wp + 8);
        f32x4 w3 = *(const f32x4*)(wp + 12);
        #pragma unroll
        for (int c = 0; c < 4; c++) {
            acc[c]      += qv * w0[c];
            acc[4 + c]  += qv * w1[c];
            acc[8 + c]  += qv * w2[c];
            acc[12 + c] += qv * w3[c];
        }
    }
    #pragma unroll
    for (int c = 0; c < H_; c++) acc[c] = wave_sum(acc[c]);
    float mx = -3e38f;
    #pragma unroll
    for (int c = 0; c < H_; c++) { acc[c] += bc[c]; mx = fmaxf(mx, acc[c]); }
    float se = 0.f;
    #pragma unroll
    for (int c = 0; c < H_; c++) { acc[c] = __expf(acc[c] - mx); se += acc[c]; }
    if (lane < H_) {
        float mycw = 0.f;
        #pragma unroll
        for (int c = 0; c < H_; c++) if (lane == c) mycw = acc[c];
        mycw /= se;
        int b = r >> 10, s = r & 1023;
        float clv = cl[r];
        mws[((size_t)(b * H_ + lane)) * S_ + s] = 1.f + clv * mycw;
    }
}

// =====================================================================
// Double softmax over one f32 attn row, in place.  Row = (b,h,q); causal
// prefix k <= q.  softmax1 over prefix (max-sub); x = attn1*m, m in [1,2)
// (no stabilization needed); final attn[k] = exp(x_k)/Z for k<=q, 1/Z
// otherwise, Z = sum_pref exp(x) + (S-1-q).  One wave per row.
// =====================================================================
__global__ __launch_bounds__(256)
void softmax2_k(float* __restrict__ attn, const float* __restrict__ mws)
{
    const int t = threadIdx.x, lane = t & 63, wave = t >> 6;
    const size_t row = (size_t)blockIdx.x * 4 + wave;     // [0, B*H*S)
    const int q = (int)(row & (S_ - 1));
    float* rp = attn + row * S_;
    const float mrow = mws[row];
    const int kb = lane * 16;

    float s[16];
    #pragma unroll
    for (int c = 0; c < 4; c++) {
        f32x4 v = *(const f32x4*)(rp + kb + c * 4);
        #pragma unroll
        for (int j = 0; j < 4; j++) s[c * 4 + j] = v[j];
    }
    float mx = -3e38f;
    #pragma unroll
    for (int j = 0; j < 16; j++) mx = fmaxf(mx, (kb + j <= q) ? s[j] : -3e38f);
    mx = wave_max(mx);

    float se = 0.f;
    #pragma unroll
    for (int j = 0; j < 16; j++) {
        float e = (kb + j <= q) ? __expf(s[j] - mx) : 0.f;
        s[j] = e; se += e;
    }
    se = wave_sum(se);

    const float scale1 = mrow / se;   // x_k = e1_k * scale1
    float s2 = 0.f;
    #pragma unroll
    for (int j = 0; j < 16; j++) {
        if (kb + j <= q) { float e2 = __expf(s[j] * scale1); s[j] = e2; s2 += e2; }
    }
    s2 = wave_sum(s2);
    const float invZ = 1.f / (s2 + (float)(S_ - 1 - q));

    #pragma unroll
    for (int c = 0; c < 4; c++) {
        f32x4 o;
        #pragma unroll
        for (int j = 0; j < 4; j++)
            o[j] = ((kb + c * 4 + j <= q) ? s[c * 4 + j] : 1.f) * invZ;
        *(f32x4*)(rp + kb + c * 4) = o;
    }
}

// ---- E x E transpose + f32 -> bf16 convert (for weights) ----
__global__ __launch_bounds__(256)
void transpose_k(const float* __restrict__ in, u16* __restrict__ out)
{
    __shared__ float tile[32][33];
    const int t = threadIdx.x;
    const int tx = t & 31, ty = t >> 5;   // ty in 0..7
    const int bx = blockIdx.x * 32, by = blockIdx.y * 32;
    #pragma unroll
    for (int i = 0; i < 32; i += 8)
        tile[ty + i][tx] = in[(size_t)(by + ty + i) * E_ + bx + tx];
    __syncthreads();
    #pragma unroll
    for (int i = 0; i < 32; i += 8)
        out[(size_t)(bx + ty + i) * E_ + by + tx] = f2bf(tile[tx][ty + i]);
}

extern "C" void kernel_launch(void* const* d_in, const int* in_sizes, int n_in,
                              void* d_out, int out_size, void* d_ws, size_t ws_size,
                              hipStream_t stream)
{
    const float* query = (const float*)d_in[0];
    const float* key_  = (const float*)d_in[1];
    const float* value = (const float*)d_in[2];
    const float* cl    = (const float*)d_in[3];
    // d_in[4] = attn_mask (tril, constant) -- causality handled analytically
    const float* Wq = (const float*)d_in[5];
    const float* bq = (const float*)d_in[6];
    const float* Wk = (const float*)d_in[7];
    const float* bk = (const float*)d_in[8];
    const float* Wv = (const float*)d_in[9];
    const float* bv = (const float*)d_in[10];
    const float* Wo = (const float*)d_in[11];
    const float* bo = (const float*)d_in[12];
    const float* Wc = (const float*)d_in[13];
    const float* bc = (const float*)d_in[14];
    const float* phib = (const float*)d_in[15];

    float* out  = (float*)d_out;
    float* attn = out + (size_t)B_ * S_ * E_;        // [B][H][S][S] f32

    // workspace layout (~42.2 MB)
    u16* q_ws   = (u16*)d_ws;                        // [B][H][S][D] bf16
    u16* k_ws   = q_ws  + (size_t)B_ * S_ * E_;      // [B][H][S][D]
    u16* vt_ws  = k_ws  + (size_t)B_ * S_ * E_;      // [B][H][D][S]
    u16* ctx_ws = vt_ws + (size_t)B_ * S_ * E_;      // [B][S][E]
    u16* wt     = ctx_ws + (size_t)B_ * S_ * E_;     // 4 x [E][E] bf16 W^T
    float* mws  = (float*)(wt + (size_t)4 * E_ * E_); // [B][H][S] f32

    const float inv_scale = 0.09826892502579689f;    // 1/(8*sqrt(PHI))
    dim3 blk(256);

    transpose_k<<<dim3(32, 32), blk, 0, stream>>>(Wq, wt);
    transpose_k<<<dim3(32, 32), blk, 0, stream>>>(Wk, wt + (size_t)E_ * E_);
    transpose_k<<<dim3(32, 32), blk, 0, stream>>>(Wv, wt + (size_t)2 * E_ * E_);
    transpose_k<<<dim3(32, 32), blk, 0, stream>>>(Wo, wt + (size_t)3 * E_ * E_);

    cons_k<<<B_ * S_ / 4, blk, 0, stream>>>(query, Wc, bc, cl, mws);

    // projections: M=4096, N=1024, K=1024 (A f32 -> bf16 staged)
    gemm_bt<128, 128, 1, true><<<dim3(8, 32, 1), blk, 0, stream>>>(
        query, E_, 0, wt, E_, 0, bq, q_ws, 0, E_, 1.f, nullptr);
    gemm_bt<128, 128, 1, true><<<dim3(8, 32, 1), blk, 0, stream>>>(
        key_, E_, 0, wt + (size_t)E_ * E_, E_, 0, bk, k_ws, 0, E_, 1.f, nullptr);
    gemm_bt<128, 128, 2, true><<<dim3(8, 32, 1), blk, 0, stream>>>(
        value, E_, 0, wt + (size_t)2 * E_ * E_, E_, 0, bv, vt_ws, 0, E_, 1.f, nullptr);

    // scores: per (b,h): M=N=1024, K=64; dense f32 write into attn region
    gemm_bt<128, 128, 3, false><<<dim3(8, 8, B_ * H_), blk, 0, stream>>>(
        q_ws, D_, (long)S_ * D_, k_ws, D_, (long)S_ * D_, nullptr,
        attn, 0, D_, inv_scale, phib);

    // double softmax in place (f32)
    softmax2_k<<<B_ * H_ * S_ / 4, blk, 0, stream>>>(attn, mws);

    // PV: per (b,h): M=1024, N=64, K=1024 (dense; A = f32 attn staged->bf16)
    gemm_bt<128, 64, 4, true><<<dim3(1, 8, B_ * H_), blk, 0, stream>>>(
        attn, S_, (long)S_ * S_, vt_ws, S_, (long)D_ * S_, nullptr,
        ctx_ws, 0, S_, 1.f, nullptr);

    // output projection: M=4096, N=1024, K=1024 (A bf16)
    gemm_bt<128, 128, 0, false><<<dim3(8, 32, 1), blk, 0, stream>>>(
        ctx_ws, E_, 0, wt + (size_t)3 * E_ * E_, E_, 0, bo, out, E_, E_, 1.f, nullptr);
}

// Round 3
// 648.692 us; speedup vs baseline: 1.1035x; 1.1035x over previous
//
#include <hip/hip_runtime.h>
#include <stdint.h>

// ---- problem constants ----
#define B_ 4
#define S_ 1024
#define E_ 1024
#define H_ 16
#define D_ 64

typedef unsigned short u16;
typedef short s16x8 __attribute__((ext_vector_type(8)));
typedef unsigned short u16x8 __attribute__((ext_vector_type(8)));
typedef unsigned short u16x4 __attribute__((ext_vector_type(4)));
typedef float f32x4 __attribute__((ext_vector_type(4)));

__device__ __forceinline__ u16 f2bf(float f) {
    union { float f; uint32_t i; } x; x.f = f;
    uint32_t r = (x.i + 0x7FFFu + ((x.i >> 16) & 1u)) >> 16;
    return (u16)r;
}

__device__ __forceinline__ float wave_sum(float v) {
    #pragma unroll
    for (int o = 32; o; o >>= 1) v += __shfl_xor(v, o);
    return v;
}

// =====================================================================
// Generic GEMM: C = A (M x K, row stride lda) * BT^T, BT is (N x K, ldb),
// BT always bf16.  A is f32 (AF32=true, converted during staging) or bf16.
// MFMA 16x16x32_bf16, 256 threads = 4 waves (2x2), wave tile (BM/2)x(BN/2).
// EPI: 0 = out proj   -> f32 C[row*ldc+col] + bias
//      1 = Q/K proj   -> bf16 [b][h][s][d] + bias
//      2 = V proj     -> bf16 [b][h][d][s] (transposed) + bias
// =====================================================================
template<int BM, int BN, int EPI, bool AF32>
__global__ __launch_bounds__(256)
void gemm_bt(const void* __restrict__ Avoid, int lda, long sA,
             const u16* __restrict__ BT, int ldb, long sB,
             const float* __restrict__ bias,
             void* __restrict__ Cvoid, int ldc, int K)
{
    constexpr int BK = 32;
    constexpr int FM = BM / 32;
    constexpr int FN = BN / 32;
    __shared__ __attribute__((aligned(16))) u16 As[BM * BK];
    __shared__ __attribute__((aligned(16))) u16 Bs[BN * BK];

    const int t = threadIdx.x;
    const int lane = t & 63;
    const int wave = t >> 6;
    const int wr = wave >> 1, wc = wave & 1;
    const int z = blockIdx.z;
    const int m0 = blockIdx.y * BM, n0 = blockIdx.x * BN;

    const u16* Bp = BT + (size_t)z * sB;

    f32x4 acc[FM][FN];
    #pragma unroll
    for (int i = 0; i < FM; i++)
        #pragma unroll
        for (int j = 0; j < FN; j++)
            acc[i][j] = (f32x4){0.f, 0.f, 0.f, 0.f};

    const int al = lane & 15;   // m (A) / n (B) / col (C)
    const int aq = lane >> 4;   // k-quad

    for (int k0 = 0; k0 < K; k0 += BK) {
        __syncthreads();
        if (AF32) {
            const float* Af = ((const float*)Avoid) + (size_t)z * sA;
            #pragma unroll
            for (int p = 0; p < (BM * BK) / 4; p += 256) {
                int c = p + t;
                int row = c >> 3, cc = c & 7;
                f32x4 v = *(const f32x4*)(Af + (size_t)(m0 + row) * lda + k0 + cc * 4);
                u16x4 o;
                o[0] = f2bf(v[0]); o[1] = f2bf(v[1]);
                o[2] = f2bf(v[2]); o[3] = f2bf(v[3]);
                *(u16x4*)(As + c * 4) = o;
            }
        } else {
            const u16* Ap = ((const u16*)Avoid) + (size_t)z * sA;
            #pragma unroll
            for (int p = 0; p < (BM * BK) / 8; p += 256) {
                int c = p + t;
                int row = c >> 2, cc = c & 3;
                u16x8 v = *(const u16x8*)(Ap + (size_t)(m0 + row) * lda + k0 + cc * 8);
                *(u16x8*)(As + c * 8) = v;
            }
        }
        #pragma unroll
        for (int p = 0; p < (BN * BK) / 8; p += 256) {
            int c = p + t;
            int row = c >> 2, cc = c & 3;
            u16x8 v = *(const u16x8*)(Bp + (size_t)(n0 + row) * ldb + k0 + cc * 8);
            *(u16x8*)(Bs + c * 8) = v;
        }
        __syncthreads();

        s16x8 af[FM], bf[FN];
        #pragma unroll
        for (int i = 0; i < FM; i++)
            af[i] = *(const s16x8*)(As + ((wr * FM + i) * 16 + al) * BK + aq * 8);
        #pragma unroll
        for (int j = 0; j < FN; j++)
            bf[j] = *(const s16x8*)(Bs + ((wc * FN + j) * 16 + al) * BK + aq * 8);
        #pragma unroll
        for (int i = 0; i < FM; i++)
            #pragma unroll
            for (int j = 0; j < FN; j++)
                acc[i][j] = __builtin_amdgcn_mfma_f32_16x16x32_bf16(af[i], bf[j], acc[i][j], 0, 0, 0);
    }

    float* Cf = (float*)Cvoid;
    u16*   Cb = (u16*)Cvoid;
    #pragma unroll
    for (int i = 0; i < FM; i++) {
        #pragma unroll
        for (int j = 0; j < FN; j++) {
            const int col = n0 + (wc * FN + j) * 16 + al;
            const float bv = bias[col];
            #pragma unroll
            for (int r = 0; r < 4; r++) {
                const int row = m0 + (wr * FM + i) * 16 + aq * 4 + r;
                float v = acc[i][j][r] + bv;
                if (EPI == 0) {
                    Cf[(size_t)row * ldc + col] = v;
                } else if (EPI == 1) {
                    int b = row >> 10, s = row & 1023, h = col >> 6, d = col & 63;
                    Cb[((size_t)((b * H_ + h) * S_ + s)) * D_ + d] = f2bf(v);
                } else { // EPI == 2
                    int b = row >> 10, s = row & 1023, h = col >> 6, d = col & 63;
                    Cb[((size_t)((b * H_ + h) * D_ + d)) * S_ + s] = f2bf(v);
                }
            }
        }
    }
}

// =====================================================================
// consciousness weights: logits = query @ Wc + bc (E x 16 f32), softmax
// over 16 heads, m = 1 + cl*cw, stored mws[(b*H+h)*S + s] (f32).
// =====================================================================
__global__ __launch_bounds__(256)
void cons_k(const float* __restrict__ query, const float* __restrict__ Wc,
            const float* __restrict__ bc, const float* __restrict__ cl,
            float* __restrict__ mws)
{
    const int t = threadIdx.x, lane = t & 63, wave = t >> 6;
    const int r = blockIdx.x * 4 + wave;   // row in [0, B*S)
    const float* qrow = query + (size_t)r * E_;
    float acc[H_];
    #pragma unroll
    for (int c = 0; c < H_; c++) acc[c] = 0.f;
    for (int e = lane; e < E_; e += 64) {
        float qv = qrow[e];
        const float* wp = Wc + e * H_;
        f32x4 w0 = *(const f32x4*)(wp);
        f32x4 w1 = *(const f32x4*)(wp + 4);
        f32x4 w2 = *(const f32x4*)(wp + 8);
        f32x4 w3 = *(const f32x4*)(wp + 12);
        #pragma unroll
        for (int c = 0; c < 4; c++) {
            acc[c]      += qv * w0[c];
            acc[4 + c]  += qv * w1[c];
            acc[8 + c]  += qv * w2[c];
            acc[12 + c] += qv * w3[c];
        }
    }
    #pragma unroll
    for (int c = 0; c < H_; c++) acc[c] = wave_sum(acc[c]);
    float mx = -3e38f;
    #pragma unroll
    for (int c = 0; c < H_; c++) { acc[c] += bc[c]; mx = fmaxf(mx, acc[c]); }
    float se = 0.f;
    #pragma unroll
    for (int c = 0; c < H_; c++) { acc[c] = __expf(acc[c] - mx); se += acc[c]; }
    if (lane < H_) {
        float mycw = 0.f;
        #pragma unroll
        for (int c = 0; c < H_; c++) if (lane == c) mycw = acc[c];
        mycw /= se;
        int b = r >> 10, s = r & 1023;
        float clv = cl[r];
        mws[((size_t)(b * H_ + lane)) * S_ + s] = 1.f + clv * mycw;
    }
}

// =====================================================================
// Fused attention: per block = one (b,h) x 32-row Q tile.
//   ph1: Sc[q][k] = alpha * (Q K^T)  via swapped-operand MFMA -> LDS f32
//        (phi_bias omitted: constant per row inside softmax1 -> cancels)
//   ph2: softmax1 (causal, max-sub) -> e1 in LDS
//   ph3: e2 = exp(e1 * m/sum1) (masked -> 1), Z = sum over ALL cols
//   ph4: PV partials (K split across 4 waves, V-frags direct from global)
//        + final attn = Sc * invZ written coalesced to d_out
//   ph5: cross-wave ctx reduction in LDS, scale by invZ, store bf16 ctx
// LDS: 32x1028 f32 score tile (pad 4 keeps 16B align, spreads banks) ~133 KB.
// =====================================================================
#define LD_ 1028
__global__ __launch_bounds__(256, 1)
void attn_fused(const u16* __restrict__ q_ws, const u16* __restrict__ k_ws,
                const u16* __restrict__ vt_ws, const float* __restrict__ mws,
                float* __restrict__ attn_out, u16* __restrict__ ctx_ws,
                float alpha)
{
    __shared__ __attribute__((aligned(16))) float sc[32 * LD_];
    __shared__ float red[8 * 32];
    __shared__ float rowmax[32], scl1[32], invz[32];

    const int t = threadIdx.x, lane = t & 63, w = t >> 6;
    const int al = lane & 15, aq = lane >> 4;
    const int bh = blockIdx.y;
    const int q0 = blockIdx.x * 32;

    const u16* Qp = q_ws + ((size_t)bh * S_ + q0) * D_;
    const u16* Kp = k_ws + (size_t)bh * S_ * D_ + (size_t)(w * 256) * D_;
    const u16* Vp = vt_ws + (size_t)bh * D_ * S_;

    // ---------- phase 1: scores ----------
    // D = mfma(K_frag, Q_frag): row(m)=k-index (4 consecutive per reg),
    // col(n)=q-index -> ds_write_b128 along k.
    s16x8 qf[2][2];
    #pragma unroll
    for (int nf = 0; nf < 2; nf++)
        #pragma unroll
        for (int ds = 0; ds < 2; ds++)
            qf[nf][ds] = *(const s16x8*)(Qp + (size_t)(nf * 16 + al) * D_ + ds * 32 + aq * 8);
    #pragma unroll
    for (int mf = 0; mf < 16; mf++) {
        const u16* kr = Kp + (size_t)(mf * 16 + al) * D_ + aq * 8;
        s16x8 kf0 = *(const s16x8*)(kr);
        s16x8 kf1 = *(const s16x8*)(kr + 32);
        f32x4 a0 = (f32x4){0.f, 0.f, 0.f, 0.f};
        f32x4 a1 = (f32x4){0.f, 0.f, 0.f, 0.f};
        a0 = __builtin_amdgcn_mfma_f32_16x16x32_bf16(kf0, qf[0][0], a0, 0, 0, 0);
        a0 = __builtin_amdgcn_mfma_f32_16x16x32_bf16(kf1, qf[0][1], a0, 0, 0, 0);
        a1 = __builtin_amdgcn_mfma_f32_16x16x32_bf16(kf0, qf[1][0], a1, 0, 0, 0);
        a1 = __builtin_amdgcn_mfma_f32_16x16x32_bf16(kf1, qf[1][1], a1, 0, 0, 0);
        const int kc = w * 256 + mf * 16 + aq * 4;
        f32x4 o0, o1;
        #pragma unroll
        for (int j = 0; j < 4; j++) { o0[j] = a0[j] * alpha; o1[j] = a1[j] * alpha; }
        *(f32x4*)(sc + (size_t)al * LD_ + kc)        = o0;
        *(f32x4*)(sc + (size_t)(16 + al) * LD_ + kc) = o1;
    }
    __syncthreads();

    // ---------- softmax passes: thread owns (row = t&31, col set cg*4 + 32k) ----------
    const int row = t & 31, cg = t >> 5;
    const int q = q0 + row;
    float* rp = sc + (size_t)row * LD_ + cg * 4;

    // pass 1: causal row max
    float mx = -3e38f;
    #pragma unroll 8
    for (int k = 0; k < 32; k++) {
        f32x4 v = *(const f32x4*)(rp + k * 32);
        const int cb = cg * 4 + k * 32;
        #pragma unroll
        for (int j = 0; j < 4; j++)
            if (cb + j <= q) mx = fmaxf(mx, v[j]);
    }
    red[cg * 32 + row] = mx;
    __syncthreads();
    if (t < 32) {
        float m = red[t];
        #pragma unroll
        for (int c = 1; c < 8; c++) m = fmaxf(m, red[c * 32 + t]);
        rowmax[t] = m;
    }
    __syncthreads();

    // pass 2: e1 = exp(s - mx) (masked -> 0), sum
    const float mxr = rowmax[row];
    float s1 = 0.f;
    #pragma unroll 8
    for (int k = 0; k < 32; k++) {
        f32x4 v = *(const f32x4*)(rp + k * 32);
        const int cb = cg * 4 + k * 32;
        f32x4 o;
        #pragma unroll
        for (int j = 0; j < 4; j++) {
            float e = (cb + j <= q) ? __expf(v[j] - mxr) : 0.f;
            o[j] = e; s1 += e;
        }
        *(f32x4*)(rp + k * 32) = o;
    }
    red[cg * 32 + row] = s1;
    __syncthreads();
    if (t < 32) {
        float s = 0.f;
        #pragma unroll
        for (int c = 0; c < 8; c++) s += red[c * 32 + t];
        scl1[t] = mws[(size_t)bh * S_ + q0 + t] / s;   // m / sum1
    }
    __syncthreads();

    // pass 3: e2 = exp(e1 * scl1) (masked -> 1), Z = sum over ALL cols
    const float sl = scl1[row];
    float s2 = 0.f;
    #pragma unroll 8
    for (int k = 0; k < 32; k++) {
        f32x4 v = *(const f32x4*)(rp + k * 32);
        const int cb = cg * 4 + k * 32;
        f32x4 o;
        #pragma unroll
        for (int j = 0; j < 4; j++) {
            float e = (cb + j <= q) ? __expf(v[j] * sl) : 1.f;
            o[j] = e; s2 += e;
        }
        *(f32x4*)(rp + k * 32) = o;
    }
    red[cg * 32 + row] = s2;
    __syncthreads();
    if (t < 32) {
        float s = 0.f;
        #pragma unroll
        for (int c = 0; c < 8; c++) s += red[c * 32 + t];
        invz[t] = 1.f / s;
    }
    __syncthreads();

    // ---------- phase 4a: PV partials, wave w covers k in [w*256, w*256+256) ----------
    f32x4 pa[2][4];
    #pragma unroll
    for (int mf = 0; mf < 2; mf++)
        #pragma unroll
        for (int nf = 0; nf < 4; nf++)
            pa[mf][nf] = (f32x4){0.f, 0.f, 0.f, 0.f};
    #pragma unroll
    for (int ks = 0; ks < 8; ks++) {
        const int kb = w * 256 + ks * 32;
        s16x8 af[2];
        #pragma unroll
        for (int mf = 0; mf < 2; mf++) {
            const float* ap = sc + (size_t)(mf * 16 + al) * LD_ + kb + aq * 8;
            f32x4 x0 = *(const f32x4*)(ap);
            f32x4 x1 = *(const f32x4*)(ap + 4);
            s16x8 pk;
            pk[0] = (short)f2bf(x0[0]); pk[1] = (short)f2bf(x0[1]);
            pk[2] = (short)f2bf(x0[2]); pk[3] = (short)f2bf(x0[3]);
            pk[4] = (short)f2bf(x1[0]); pk[5] = (short)f2bf(x1[1]);
            pk[6] = (short)f2bf(x1[2]); pk[7] = (short)f2bf(x1[3]);
            af[mf] = pk;
        }
        #pragma unroll
        for (int nf = 0; nf < 4; nf++) {
            s16x8 bf = *(const s16x8*)(Vp + (size_t)(nf * 16 + al) * S_ + kb + aq * 8);
            pa[0][nf] = __builtin_amdgcn_mfma_f32_16x16x32_bf16(af[0], bf, pa[0][nf], 0, 0, 0);
            pa[1][nf] = __builtin_amdgcn_mfma_f32_16x16x32_bf16(af[1], bf, pa[1][nf], 0, 0, 0);
        }
    }

    // ---------- phase 4b: final attn write (coalesced), wave w rows 8w..8w+7 ----------
    float* ao = attn_out + (size_t)bh * S_ * S_ + (size_t)q0 * S_;
    #pragma unroll
    for (int rr = 0; rr < 8; rr++) {
        const int r2 = w * 8 + rr;
        const float iz = invz[r2];
        #pragma unroll
        for (int k2 = 0; k2 < 4; k2++) {
            f32x4 v = *(const f32x4*)(sc + (size_t)r2 * LD_ + k2 * 256 + lane * 4);
            f32x4 o;
            #pragma unroll
            for (int j = 0; j < 4; j++) o[j] = v[j] * iz;
            *(f32x4*)(ao + (size_t)r2 * S_ + k2 * 256 + lane * 4) = o;
        }
    }
    __syncthreads();   // all Sc reads done -> reuse as reduction scratch

    // ---------- phase 5: dump partials [w][d(64)][36], reduce, store ctx ----------
    {
        float* dp = sc + w * (64 * 36);
        #pragma unroll
        for (int nf = 0; nf < 4; nf++)
            #pragma unroll
            for (int mf = 0; mf < 2; mf++)
                *(f32x4*)(dp + (size_t)(nf * 16 + al) * 36 + mf * 16 + aq * 4) = pa[mf][nf];
    }
    __syncthreads();
    {
        const int r5 = t & 31, d0 = (t >> 5) * 8;
        const float iz = invz[r5];
        float o[8];
        #pragma unroll
        for (int dd = 0; dd < 8; dd++) o[dd] = 0.f;
        #pragma unroll
        for (int ww = 0; ww < 4; ww++) {
            const float* rp5 = sc + ww * (64 * 36) + r5;
            #pragma unroll
            for (int dd = 0; dd < 8; dd++) o[dd] += rp5[(size_t)(d0 + dd) * 36];
        }
        u16x8 ob;
        #pragma unroll
        for (int dd = 0; dd < 8; dd++) ob[dd] = f2bf(o[dd] * iz);
        const int b = bh >> 4, h = bh & 15;
        *(u16x8*)(ctx_ws + ((size_t)(b * S_ + q0 + r5)) * E_ + h * 64 + d0) = ob;
    }
}

// ---- E x E transpose + f32 -> bf16 convert (for weights) ----
__global__ __launch_bounds__(256)
void transpose_k(const float* __restrict__ in, u16* __restrict__ out)
{
    __shared__ float tile[32][33];
    const int t = threadIdx.x;
    const int tx = t & 31, ty = t >> 5;
    const int bx = blockIdx.x * 32, by = blockIdx.y * 32;
    #pragma unroll
    for (int i = 0; i < 32; i += 8)
        tile[ty + i][tx] = in[(size_t)(by + ty + i) * E_ + bx + tx];
    __syncthreads();
    #pragma unroll
    for (int i = 0; i < 32; i += 8)
        out[(size_t)(bx + ty + i) * E_ + by + tx] = f2bf(tile[tx][ty + i]);
}

extern "C" void kernel_launch(void* const* d_in, const int* in_sizes, int n_in,
                              void* d_out, int out_size, void* d_ws, size_t ws_size,
                              hipStream_t stream)
{
    const float* query = (const float*)d_in[0];
    const float* key_  = (const float*)d_in[1];
    const float* value = (const float*)d_in[2];
    const float* cl    = (const float*)d_in[3];
    // d_in[4] = attn_mask (tril, constant) -- causality handled analytically
    const float* Wq = (const float*)d_in[5];
    const float* bq = (const float*)d_in[6];
    const float* Wk = (const float*)d_in[7];
    const float* bk = (const float*)d_in[8];
    const float* Wv = (const float*)d_in[9];
    const float* bv = (const float*)d_in[10];
    const float* Wo = (const float*)d_in[11];
    const float* bo = (const float*)d_in[12];
    const float* Wc = (const float*)d_in[13];
    const float* bc = (const float*)d_in[14];
    // d_in[15] = phi_bias: per-row constant inside softmax1 -> no effect on outputs

    float* out  = (float*)d_out;
    float* attn = out + (size_t)B_ * S_ * E_;        // [B][H][S][S] f32

    u16* q_ws   = (u16*)d_ws;                        // [B][H][S][D] bf16
    u16* k_ws   = q_ws  + (size_t)B_ * S_ * E_;      // [B][H][S][D]
    u16* vt_ws  = k_ws  + (size_t)B_ * S_ * E_;      // [B][H][D][S]
    u16* ctx_ws = vt_ws + (size_t)B_ * S_ * E_;      // [B][S][E]
    u16* wt     = ctx_ws + (size_t)B_ * S_ * E_;     // 4 x [E][E] bf16 W^T
    float* mws  = (float*)(wt + (size_t)4 * E_ * E_); // [B][H][S] f32

    const float inv_scale = 0.09826892502579689f;    // 1/(8*sqrt(PHI))
    dim3 blk(256);

    transpose_k<<<dim3(32, 32), blk, 0, stream>>>(Wq, wt);
    transpose_k<<<dim3(32, 32), blk, 0, stream>>>(Wk, wt + (size_t)E_ * E_);
    transpose_k<<<dim3(32, 32), blk, 0, stream>>>(Wv, wt + (size_t)2 * E_ * E_);
    transpose_k<<<dim3(32, 32), blk, 0, stream>>>(Wo, wt + (size_t)3 * E_ * E_);

    cons_k<<<B_ * S_ / 4, blk, 0, stream>>>(query, Wc, bc, cl, mws);

    // projections: M=4096, N=1024, K=1024 (A f32 -> bf16 staged)
    gemm_bt<128, 128, 1, true><<<dim3(8, 32, 1), blk, 0, stream>>>(
        query, E_, 0, wt, E_, 0, bq, q_ws, 0, E_);
    gemm_bt<128, 128, 1, true><<<dim3(8, 32, 1), blk, 0, stream>>>(
        key_, E_, 0, wt + (size_t)E_ * E_, E_, 0, bk, k_ws, 0, E_);
    gemm_bt<128, 128, 2, true><<<dim3(8, 32, 1), blk, 0, stream>>>(
        value, E_, 0, wt + (size_t)2 * E_ * E_, E_, 0, bv, vt_ws, 0, E_);

    // fused scores + double-softmax + attn write + PV
    attn_fused<<<dim3(S_ / 32, B_ * H_), blk, 0, stream>>>(
        q_ws, k_ws, vt_ws, mws, attn, ctx_ws, inv_scale);

    // output projection: M=4096, N=1024, K=1024 (A bf16)
    gemm_bt<128, 128, 0, false><<<dim3(8, 32, 1), blk, 0, stream>>>(
        ctx_ws, E_, 0, wt + (size_t)3 * E_ * E_, E_, 0, bo, out, E_, E_);
}

// Round 4
// 591.607 us; speedup vs baseline: 1.2100x; 1.0965x over previous
//
#include <hip/hip_runtime.h>
#include <stdint.h>

// ---- problem constants ----
#define B_ 4
#define S_ 1024
#define E_ 1024
#define H_ 16
#define D_ 64

typedef unsigned short u16;
typedef short s16x8 __attribute__((ext_vector_type(8)));
typedef unsigned short u16x8 __attribute__((ext_vector_type(8)));
typedef unsigned short u16x4 __attribute__((ext_vector_type(4)));
typedef float f32x4 __attribute__((ext_vector_type(4)));

__device__ __forceinline__ u16 f2bf(float f) {
    union { float f; uint32_t i; } x; x.f = f;
    uint32_t r = (x.i + 0x7FFFu + ((x.i >> 16) & 1u)) >> 16;
    return (u16)r;
}

__device__ __forceinline__ float wave_sum(float v) {
    #pragma unroll
    for (int o = 32; o; o >>= 1) v += __shfl_xor(v, o);
    return v;
}

// =====================================================================
// Generic GEMM: C = A (M x K, row stride lda) * BT^T, BT is (N x K, ldb),
// BT always bf16.  A is f32 (AF32=true, converted during staging) or bf16.
// Register-buffered pipeline: next K-tile loaded to regs during compute,
// so global latency overlaps ds_read+MFMA instead of stalling ds_write.
// 256 threads = 4 waves (2x2), wave tile (BM/2)x(BN/2).
// EPI: 0 = out proj   -> f32 C[row*ldc+col] + bias
//      1 = Q/K proj   -> bf16 [b][h][s][d] + bias
//      2 = V proj     -> bf16 [b][h][d][s] (transposed) + bias
// =====================================================================
template<int BM, int BN, int EPI, bool AF32>
__global__ __launch_bounds__(256, 2)
void gemm_bt(const void* __restrict__ Avoid, int lda, long sA,
             const u16* __restrict__ BT, int ldb, long sB,
             const float* __restrict__ bias,
             void* __restrict__ Cvoid, int ldc, int K)
{
    constexpr int BK = 32;
    constexpr int FM = BM / 32;
    constexpr int FN = BN / 32;
    constexpr int NAF = (BM * BK) / 4 / 256;   // f32x4 chunks/thread (AF32)
    constexpr int NAB = (BM * BK) / 8 / 256;   // u16x8 chunks/thread (bf16)
    constexpr int NB  = (BN * BK) / 8 / 256;
    __shared__ __attribute__((aligned(16))) u16 As[BM * BK];
    __shared__ __attribute__((aligned(16))) u16 Bs[BN * BK];

    const int t = threadIdx.x;
    const int lane = t & 63;
    const int wave = t >> 6;
    const int wr = wave >> 1, wc = wave & 1;
    const int z = blockIdx.z;
    const int m0 = blockIdx.y * BM, n0 = blockIdx.x * BN;

    const float* Af = ((const float*)Avoid) + (size_t)z * sA;
    const u16*  Ab  = ((const u16*)Avoid) + (size_t)z * sA;
    const u16*  Bp  = BT + (size_t)z * sB;

    f32x4 ra[NAF];
    u16x8 rab[NAB];
    u16x8 rb[NB];

    auto loadA = [&](int k0) {
        if constexpr (AF32) {
            #pragma unroll
            for (int i = 0; i < NAF; i++) {
                int c = i * 256 + t, row = c >> 3, cc = c & 7;
                ra[i] = *(const f32x4*)(Af + (size_t)(m0 + row) * lda + k0 + cc * 4);
            }
        } else {
            #pragma unroll
            for (int i = 0; i < NAB; i++) {
                int c = i * 256 + t, row = c >> 2, cc = c & 3;
                rab[i] = *(const u16x8*)(Ab + (size_t)(m0 + row) * lda + k0 + cc * 8);
            }
        }
    };
    auto loadB = [&](int k0) {
        #pragma unroll
        for (int i = 0; i < NB; i++) {
            int c = i * 256 + t, row = c >> 2, cc = c & 3;
            rb[i] = *(const u16x8*)(Bp + (size_t)(n0 + row) * ldb + k0 + cc * 8);
        }
    };
    auto storeLDS = [&]() {
        if constexpr (AF32) {
            #pragma unroll
            for (int i = 0; i < NAF; i++) {
                int c = i * 256 + t;
                u16x4 o;
                o[0] = f2bf(ra[i][0]); o[1] = f2bf(ra[i][1]);
                o[2] = f2bf(ra[i][2]); o[3] = f2bf(ra[i][3]);
                *(u16x4*)(As + c * 4) = o;
            }
        } else {
            #pragma unroll
            for (int i = 0; i < NAB; i++) {
                int c = i * 256 + t;
                *(u16x8*)(As + c * 8) = rab[i];
            }
        }
        #pragma unroll
        for (int i = 0; i < NB; i++) {
            int c = i * 256 + t;
            *(u16x8*)(Bs + c * 8) = rb[i];
        }
    };

    f32x4 acc[FM][FN];
    #pragma unroll
    for (int i = 0; i < FM; i++)
        #pragma unroll
        for (int j = 0; j < FN; j++)
            acc[i][j] = (f32x4){0.f, 0.f, 0.f, 0.f};

    const int al = lane & 15;
    const int aq = lane >> 4;

    loadA(0); loadB(0);
    for (int k0 = 0; k0 < K; k0 += BK) {
        __syncthreads();
        storeLDS();
        __syncthreads();
        if (k0 + BK < K) { loadA(k0 + BK); loadB(k0 + BK); }  // prefetch next

        s16x8 af[FM], bf[FN];
        #pragma unroll
        for (int i = 0; i < FM; i++)
            af[i] = *(const s16x8*)(As + ((wr * FM + i) * 16 + al) * BK + aq * 8);
        #pragma unroll
        for (int j = 0; j < FN; j++)
            bf[j] = *(const s16x8*)(Bs + ((wc * FN + j) * 16 + al) * BK + aq * 8);
        #pragma unroll
        for (int i = 0; i < FM; i++)
            #pragma unroll
            for (int j = 0; j < FN; j++)
                acc[i][j] = __builtin_amdgcn_mfma_f32_16x16x32_bf16(af[i], bf[j], acc[i][j], 0, 0, 0);
    }

    float* Cf = (float*)Cvoid;
    u16*   Cb = (u16*)Cvoid;
    #pragma unroll
    for (int i = 0; i < FM; i++) {
        #pragma unroll
        for (int j = 0; j < FN; j++) {
            const int col = n0 + (wc * FN + j) * 16 + al;
            const float bv = bias[col];
            #pragma unroll
            for (int r = 0; r < 4; r++) {
                const int row = m0 + (wr * FM + i) * 16 + aq * 4 + r;
                float v = acc[i][j][r] + bv;
                if (EPI == 0) {
                    Cf[(size_t)row * ldc + col] = v;
                } else if (EPI == 1) {
                    int b = row >> 10, s = row & 1023, h = col >> 6, d = col & 63;
                    Cb[((size_t)((b * H_ + h) * S_ + s)) * D_ + d] = f2bf(v);
                } else { // EPI == 2
                    int b = row >> 10, s = row & 1023, h = col >> 6, d = col & 63;
                    Cb[((size_t)((b * H_ + h) * D_ + d)) * S_ + s] = f2bf(v);
                }
            }
        }
    }
}

// =====================================================================
// consciousness weights: logits = query @ Wc + bc (E x 16 f32), softmax
// over 16 heads, m = 1 + cl*cw, stored mws[(b*H+h)*S + s] (f32).
// =====================================================================
__global__ __launch_bounds__(256)
void cons_k(const float* __restrict__ query, const float* __restrict__ Wc,
            const float* __restrict__ bc, const float* __restrict__ cl,
            float* __restrict__ mws)
{
    const int t = threadIdx.x, lane = t & 63, wave = t >> 6;
    const int r = blockIdx.x * 4 + wave;   // row in [0, B*S)
    const float* qrow = query + (size_t)r * E_;
    float acc[H_];
    #pragma unroll
    for (int c = 0; c < H_; c++) acc[c] = 0.f;
    for (int e = lane; e < E_; e += 64) {
        float qv = qrow[e];
        const float* wp = Wc + e * H_;
        f32x4 w0 = *(const f32x4*)(wp);
        f32x4 w1 = *(const f32x4*)(wp + 4);
        f32x4 w2 = *(const f32x4*)(wp + 8);
        f32x4 w3 = *(const f32x4*)(wp + 12);
        #pragma unroll
        for (int c = 0; c < 4; c++) {
            acc[c]      += qv * w0[c];
            acc[4 + c]  += qv * w1[c];
            acc[8 + c]  += qv * w2[c];
            acc[12 + c] += qv * w3[c];
        }
    }
    #pragma unroll
    for (int c = 0; c < H_; c++) acc[c] = wave_sum(acc[c]);
    float mx = -3e38f;
    #pragma unroll
    for (int c = 0; c < H_; c++) { acc[c] += bc[c]; mx = fmaxf(mx, acc[c]); }
    float se = 0.f;
    #pragma unroll
    for (int c = 0; c < H_; c++) { acc[c] = __expf(acc[c] - mx); se += acc[c]; }
    if (lane < H_) {
        float mycw = 0.f;
        #pragma unroll
        for (int c = 0; c < H_; c++) if (lane == c) mycw = acc[c];
        mycw /= se;
        int b = r >> 10, s = r & 1023;
        float clv = cl[r];
        mws[((size_t)(b * H_ + lane)) * S_ + s] = 1.f + clv * mycw;
    }
}

// =====================================================================
// Fused attention: per block = one (b,h) x 16-row Q tile (67 KB LDS ->
// 2 blocks/CU so phases of co-resident blocks overlap).
//   ph1: Sc[q][k] = alpha*(Q K^T) via swapped-operand MFMA -> LDS f32
//   ph2: softmax1 (causal, max-sub) -> e1 in LDS
//   ph3: e2 = exp(e1 * m/sum1) (masked -> 1), Z = sum over ALL cols
//   ph4: PV partials (K split across 4 waves, V-frags from global)
//        + final attn = Sc * invZ written coalesced to d_out
//   ph5: cross-wave ctx reduction in LDS, scale by invZ, store bf16 ctx
// =====================================================================
#define LD_ 1028
__global__ __launch_bounds__(256, 2)
void attn_fused(const u16* __restrict__ q_ws, const u16* __restrict__ k_ws,
                const u16* __restrict__ vt_ws, const float* __restrict__ mws,
                float* __restrict__ attn_out, u16* __restrict__ ctx_ws,
                float alpha)
{
    __shared__ __attribute__((aligned(16))) float sc[16 * LD_];
    __shared__ float red[16 * 16];
    __shared__ float rowmax[16], scl1[16], invz[16];

    const int t = threadIdx.x, lane = t & 63, w = t >> 6;
    const int al = lane & 15, aq = lane >> 4;
    const int bh = blockIdx.y;
    const int q0 = blockIdx.x * 16;

    const u16* Qp = q_ws + ((size_t)bh * S_ + q0) * D_;
    const u16* Kp = k_ws + (size_t)bh * S_ * D_ + (size_t)(w * 256) * D_;
    const u16* Vp = vt_ws + (size_t)bh * D_ * S_;

    // ---------- phase 1: scores ----------
    // D = mfma(K_frag, Q_frag): row(m)=k-index (4 consecutive per reg),
    // col(n)=q-index -> f32x4 store along k.
    s16x8 qf0 = *(const s16x8*)(Qp + (size_t)al * D_ + aq * 8);
    s16x8 qf1 = *(const s16x8*)(Qp + (size_t)al * D_ + 32 + aq * 8);
    #pragma unroll
    for (int mf = 0; mf < 16; mf++) {
        const u16* kr = Kp + (size_t)(mf * 16 + al) * D_ + aq * 8;
        s16x8 kf0 = *(const s16x8*)(kr);
        s16x8 kf1 = *(const s16x8*)(kr + 32);
        f32x4 a0 = (f32x4){0.f, 0.f, 0.f, 0.f};
        a0 = __builtin_amdgcn_mfma_f32_16x16x32_bf16(kf0, qf0, a0, 0, 0, 0);
        a0 = __builtin_amdgcn_mfma_f32_16x16x32_bf16(kf1, qf1, a0, 0, 0, 0);
        const int kc = w * 256 + mf * 16 + aq * 4;
        f32x4 o;
        #pragma unroll
        for (int j = 0; j < 4; j++) o[j] = a0[j] * alpha;
        *(f32x4*)(sc + (size_t)al * LD_ + kc) = o;
    }
    __syncthreads();

    // ---------- softmax: thread owns (row = t&15, cols cg*4 + 64k) ----------
    const int row = t & 15, cg = t >> 4;
    const int q = q0 + row;
    float* rp = sc + (size_t)row * LD_ + cg * 4;

    // pass 1: causal row max
    float mx = -3e38f;
    #pragma unroll 4
    for (int k = 0; k < 16; k++) {
        f32x4 v = *(const f32x4*)(rp + k * 64);
        const int cb = cg * 4 + k * 64;
        #pragma unroll
        for (int j = 0; j < 4; j++)
            if (cb + j <= q) mx = fmaxf(mx, v[j]);
    }
    red[cg * 16 + row] = mx;
    __syncthreads();
    if (t < 16) {
        float m = red[t];
        #pragma unroll
        for (int c = 1; c < 16; c++) m = fmaxf(m, red[c * 16 + t]);
        rowmax[t] = m;
    }
    __syncthreads();

    // pass 2: e1 = exp(s - mx) (masked -> 0), sum
    const float mxr = rowmax[row];
    float s1 = 0.f;
    #pragma unroll 4
    for (int k = 0; k < 16; k++) {
        f32x4 v = *(const f32x4*)(rp + k * 64);
        const int cb = cg * 4 + k * 64;
        f32x4 o;
        #pragma unroll
        for (int j = 0; j < 4; j++) {
            float e = (cb + j <= q) ? __expf(v[j] - mxr) : 0.f;
            o[j] = e; s1 += e;
        }
        *(f32x4*)(rp + k * 64) = o;
    }
    red[cg * 16 + row] = s1;
    __syncthreads();
    if (t < 16) {
        float s = 0.f;
        #pragma unroll
        for (int c = 0; c < 16; c++) s += red[c * 16 + t];
        scl1[t] = mws[(size_t)bh * S_ + q0 + t] / s;   // m / sum1
    }
    __syncthreads();

    // pass 3: e2 = exp(e1 * scl1) (masked -> 1), Z over ALL cols
    const float sl = scl1[row];
    float s2 = 0.f;
    #pragma unroll 4
    for (int k = 0; k < 16; k++) {
        f32x4 v = *(const f32x4*)(rp + k * 64);
        const int cb = cg * 4 + k * 64;
        f32x4 o;
        #pragma unroll
        for (int j = 0; j < 4; j++) {
            float e = (cb + j <= q) ? __expf(v[j] * sl) : 1.f;
            o[j] = e; s2 += e;
        }
        *(f32x4*)(rp + k * 64) = o;
    }
    red[cg * 16 + row] = s2;
    __syncthreads();
    if (t < 16) {
        float s = 0.f;
        #pragma unroll
        for (int c = 0; c < 16; c++) s += red[c * 16 + t];
        invz[t] = 1.f / s;
    }
    __syncthreads();

    // ---------- phase 4a: PV partials, wave w covers k in [w*256, w*256+256) ----------
    f32x4 pa[4];
    #pragma unroll
    for (int nf = 0; nf < 4; nf++) pa[nf] = (f32x4){0.f, 0.f, 0.f, 0.f};
    #pragma unroll
    for (int ks = 0; ks < 8; ks++) {
        const int kb = w * 256 + ks * 32;
        const float* ap = sc + (size_t)al * LD_ + kb + aq * 8;
        f32x4 x0 = *(const f32x4*)(ap);
        f32x4 x1 = *(const f32x4*)(ap + 4);
        s16x8 af;
        af[0] = (short)f2bf(x0[0]); af[1] = (short)f2bf(x0[1]);
        af[2] = (short)f2bf(x0[2]); af[3] = (short)f2bf(x0[3]);
        af[4] = (short)f2bf(x1[0]); af[5] = (short)f2bf(x1[1]);
        af[6] = (short)f2bf(x1[2]); af[7] = (short)f2bf(x1[3]);
        #pragma unroll
        for (int nf = 0; nf < 4; nf++) {
            s16x8 bf = *(const s16x8*)(Vp + (size_t)(nf * 16 + al) * S_ + kb + aq * 8);
            pa[nf] = __builtin_amdgcn_mfma_f32_16x16x32_bf16(af, bf, pa[nf], 0, 0, 0);
        }
    }

    // ---------- phase 4b: final attn write (coalesced), wave w rows 4w..4w+3 ----------
    float* ao = attn_out + (size_t)bh * S_ * S_ + (size_t)q0 * S_;
    #pragma unroll
    for (int rr = 0; rr < 4; rr++) {
        const int r2 = w * 4 + rr;
        const float iz = invz[r2];
        #pragma unroll
        for (int k2 = 0; k2 < 4; k2++) {
            f32x4 v = *(const f32x4*)(sc + (size_t)r2 * LD_ + k2 * 256 + lane * 4);
            f32x4 o;
            #pragma unroll
            for (int j = 0; j < 4; j++) o[j] = v[j] * iz;
            *(f32x4*)(ao + (size_t)r2 * S_ + k2 * 256 + lane * 4) = o;
        }
    }
    __syncthreads();   // all Sc reads done -> reuse as reduction scratch

    // ---------- phase 5: dump partials [w][d(64)][row16+pad], reduce, store ----------
    {
        float* dp = sc + w * (64 * 20);
        #pragma unroll
        for (int nf = 0; nf < 4; nf++)
            *(f32x4*)(dp + (size_t)(nf * 16 + al) * 20 + aq * 4) = pa[nf];
    }
    __syncthreads();
    {
        const int r5 = t >> 4, d0 = (t & 15) * 4;
        const float iz = invz[r5];
        float o[4] = {0.f, 0.f, 0.f, 0.f};
        #pragma unroll
        for (int ww = 0; ww < 4; ww++) {
            const float* rp5 = sc + ww * (64 * 20) + r5;
            #pragma unroll
            for (int dd = 0; dd < 4; dd++) o[dd] += rp5[(size_t)(d0 + dd) * 20];
        }
        u16x4 ob;
        #pragma unroll
        for (int dd = 0; dd < 4; dd++) ob[dd] = f2bf(o[dd] * iz);
        const int b = bh >> 4, h = bh & 15;
        *(u16x4*)(ctx_ws + ((size_t)(b * S_ + q0 + r5)) * E_ + h * 64 + d0) = ob;
    }
}

// ---- 4 x (E x E transpose + f32 -> bf16 convert), one dispatch ----
__global__ __launch_bounds__(256)
void transpose4_k(const float* __restrict__ W0, const float* __restrict__ W1,
                  const float* __restrict__ W2, const float* __restrict__ W3,
                  u16* __restrict__ out)
{
    __shared__ float tile[32][33];
    const int zz = blockIdx.z;
    const float* in = (zz == 0) ? W0 : (zz == 1) ? W1 : (zz == 2) ? W2 : W3;
    u16* o = out + (size_t)zz * E_ * E_;
    const int t = threadIdx.x;
    const int tx = t & 31, ty = t >> 5;
    const int bx = blockIdx.x * 32, by = blockIdx.y * 32;
    #pragma unroll
    for (int i = 0; i < 32; i += 8)
        tile[ty + i][tx] = in[(size_t)(by + ty + i) * E_ + bx + tx];
    __syncthreads();
    #pragma unroll
    for (int i = 0; i < 32; i += 8)
        o[(size_t)(bx + ty + i) * E_ + by + tx] = f2bf(tile[tx][ty + i]);
}

extern "C" void kernel_launch(void* const* d_in, const int* in_sizes, int n_in,
                              void* d_out, int out_size, void* d_ws, size_t ws_size,
                              hipStream_t stream)
{
    const float* query = (const float*)d_in[0];
    const float* key_  = (const float*)d_in[1];
    const float* value = (const float*)d_in[2];
    const float* cl    = (const float*)d_in[3];
    // d_in[4] = attn_mask (tril, constant) -- causality handled analytically
    const float* Wq = (const float*)d_in[5];
    const float* bq = (const float*)d_in[6];
    const float* Wk = (const float*)d_in[7];
    const float* bk = (const float*)d_in[8];
    const float* Wv = (const float*)d_in[9];
    const float* bv = (const float*)d_in[10];
    const float* Wo = (const float*)d_in[11];
    const float* bo = (const float*)d_in[12];
    const float* Wc = (const float*)d_in[13];
    const float* bc = (const float*)d_in[14];
    // d_in[15] = phi_bias: per-row constant inside softmax1 -> cancels

    float* out  = (float*)d_out;
    float* attn = out + (size_t)B_ * S_ * E_;        // [B][H][S][S] f32

    u16* q_ws   = (u16*)d_ws;                        // [B][H][S][D] bf16
    u16* k_ws   = q_ws  + (size_t)B_ * S_ * E_;      // [B][H][S][D]
    u16* vt_ws  = k_ws  + (size_t)B_ * S_ * E_;      // [B][H][D][S]
    u16* ctx_ws = vt_ws + (size_t)B_ * S_ * E_;      // [B][S][E]
    u16* wt     = ctx_ws + (size_t)B_ * S_ * E_;     // 4 x [E][E] bf16 W^T
    float* mws  = (float*)(wt + (size_t)4 * E_ * E_); // [B][H][S] f32

    const float inv_scale = 0.09826892502579689f;    // 1/(8*sqrt(PHI))
    dim3 blk(256);

    transpose4_k<<<dim3(32, 32, 4), blk, 0, stream>>>(Wq, Wk, Wv, Wo, wt);

    cons_k<<<B_ * S_ / 4, blk, 0, stream>>>(query, Wc, bc, cl, mws);

    // projections: M=4096, N=1024, K=1024 (A f32 -> bf16 staged); 512 blocks
    gemm_bt<128, 64, 1, true><<<dim3(16, 32, 1), blk, 0, stream>>>(
        query, E_, 0, wt, E_, 0, bq, q_ws, 0, E_);
    gemm_bt<128, 64, 1, true><<<dim3(16, 32, 1), blk, 0, stream>>>(
        key_, E_, 0, wt + (size_t)E_ * E_, E_, 0, bk, k_ws, 0, E_);
    gemm_bt<128, 64, 2, true><<<dim3(16, 32, 1), blk, 0, stream>>>(
        value, E_, 0, wt + (size_t)2 * E_ * E_, E_, 0, bv, vt_ws, 0, E_);

    // fused scores + double-softmax + attn write + PV (16-row Q tiles)
    attn_fused<<<dim3(S_ / 16, B_ * H_), blk, 0, stream>>>(
        q_ws, k_ws, vt_ws, mws, attn, ctx_ws, inv_scale);

    // output projection: M=4096, N=1024, K=1024 (A bf16); 512 blocks
    gemm_bt<128, 64, 0, false><<<dim3(16, 32, 1), blk, 0, stream>>>(
        ctx_ws, E_, 0, wt + (size_t)3 * E_ * E_, E_, 0, bo, out, E_, E_);
}